// Round 7
// baseline (223.758 us; speedup 1.0000x reference)
//
#include <hip/hip_runtime.h>
#include <hip/hip_bf16.h>
#include <math.h>

constexpr int kB = 128;
constexpr int kT = 256;
constexpr int kC = 384;
constexpr int kH = 64;

using bf16x8 = __attribute__((ext_vector_type(8))) short;  // 8 bf16 = 4 VGPRs
using f32x4  = __attribute__((ext_vector_type(4))) float;

union BF4 { short4 s; __hip_bfloat162 h[2]; };

__device__ inline short4 cvt4(float4 a) {
    BF4 u;
    u.h[0] = __float22bfloat162_rn(float2{a.x, a.y});
    u.h[1] = __float22bfloat162_rn(float2{a.z, a.w});
    return u.s;
}
__device__ inline short bf1(float f) {
    __hip_bfloat16 h = __float2bfloat16(f);
    return *(short*)&h;
}

// ---------------------------------------------------------------------------
// Kernel 0: Wt[n][k] bf16, n in [0,192) = (w*64+h), k in [0,384).
// Wk rows pre-scaled by 384^-0.5 (k only feeds scores).
// ---------------------------------------------------------------------------
__global__ void prep_kernel(const float* __restrict__ Wq,
                            const float* __restrict__ Wk,
                            const float* __restrict__ Wv,
                            __hip_bfloat16* __restrict__ Wt) {
    int idx = blockIdx.x * 256 + threadIdx.x;     // [0, 192*384)
    int n = idx / kC, c = idx % kC;
    int w = n >> 6, h = n & 63;
    const float* W = (w == 0) ? Wq : (w == 1) ? Wk : Wv;
    float val = W[c * kH + h];
    if (w == 1) val *= 0.051031036307982884f;     // 384^-0.5
    Wt[idx] = __float2bfloat16(val);
}

// ---------------------------------------------------------------------------
// Fused kernel — occupancy rebuild: LDS 153.6 KB -> 80.0 KB => 2 blocks/CU
// (4 waves/SIMD, and the two blocks are barrier-INDEPENDENT, unlike R2's
// more-waves-same-barriers attempt). Three enabling changes:
//  1. Staging (As/Bs, 64.5 KB) ALIASES the homes (Qs/Ks/VTs, 80 KB): staging
//     is dead after the last mstep's barrier, homes are written only in the
//     epilogue after that barrier.
//  2. Homes are unpadded + XOR-swizzled (idx ^ ((row&7)<<3) in shorts): all
//     phase-2 b128 reads land in the 2-way class (free, m136); padding
//     removed saves the 9.6 KB that wouldn't fit.
//  3. P never touches LDS: the S'->A-fragment redistribution is same-m16
//     cross-quad, done with 8 cvt_pk + 16 __shfl per i-tile (static indices).
// Phase 1 reverted to R1's 1-deep pipeline (2-deep was neutral R5 vs R1 and
// costs ~24 VGPR; (512,4) caps at 128 — R1's phase 1 measured 104).
// Phase 2 keeps R6's batch softmax. Block = (b, half), XCD pair swizzle,
// dead-K skip unchanged.
// ---------------------------------------------------------------------------
__global__ __launch_bounds__(512, 4) void fused_kernel(
    const float* __restrict__ x, const __hip_bfloat16* __restrict__ Wt,
    float* __restrict__ out)
{
    __shared__ __align__(16) short SM[40960];      // 81920 B exactly
    // homes (live from epilogue on):
    short* Qs  = SM;              // [s][h] 256x64, idx (s*64+h)^((s&7)<<3)
    short* Ks  = SM + 16384;      // [t-t0][h] 128x64, same swizzle
    short* VTs = SM + 24576;      // [h][s] 64x256, idx (h*256+s)^((h&7)<<3)
    // staging (live during phase 1 only, aliases homes):
    short* As0 = SM;              // x tile bf16 [m][kk], stride 36
    short* As1 = SM + 9216;
    short* Bs0 = SM + 18432;      // Wt tile [n][kk], stride 36
    short* Bs1 = SM + 25344;      // ends at 32256 shorts = 64512 B

    const int bid  = blockIdx.x;
    const int b    = ((bid >> 4) << 3) | (bid & 7);   // batch
    const int half = ((bid >> 3) & 1) ^ 1;            // heavy (1) first
    const int t0   = half * 128;

    const int tid  = threadIdx.x;
    const int wave = tid >> 6, lane = tid & 63;
    const int m16  = lane & 15, quad = lane >> 4;
    const int wm = wave & 1, wn = wave >> 1;       // m-half, 3-n-tile slice
    const short* wt = (const short*)Wt;
    const float* xb = x + (size_t)b * kT * kC;

    // swizzled home indexers (short units; XOR bits 3..5 keep 8-short groups
    // intact -> b128/short4 alignment preserved)
    auto QI = [](int s, int h) { return ((s << 6) + h) ^ ((s & 7) << 3); };
    auto VI = [](int h, int s) { return ((h << 8) + s) ^ ((h & 7) << 3); };

    // wave-uniform activity masks for the light half (M = 128)
    const bool mfmaAct = (half == 1) || (wm == 0);

    // dead-K: heavy half's rows 0-127 K-projection is discarded -> skip
    bool kskip[3];
#pragma unroll
    for (int j = 0; j < 3; ++j) {
        const int nt = wn * 3 + j;
        kskip[j] = (half == 1) && (wm == 0) && (nt >= 4) && (nt < 8);
    }

    // ---------------- Phase 1: projection (R1 1-deep pipeline) -------------
    const int arow = tid >> 1, acol = (tid & 1) * 16;
    const bool aAct = (half == 1) || (arow < 128);

    float4 la[4]; bf16x8 lb0, lb1;
    auto glod = [&](int k0) {
        if (aAct) {
#pragma unroll
            for (int i = 0; i < 4; ++i)
                la[i] = *(const float4*)(xb + (size_t)arow * kC + k0 + acol + 4 * i);
        }
        {
            int n = tid >> 2, kk = (tid & 3) * 8;
            lb0 = *(const bf16x8*)(wt + (size_t)n * kC + k0 + kk);
        }
        if (tid < 256) {
            int c = tid + 512;
            int n = c >> 2, kk = (c & 3) * 8;
            lb1 = *(const bf16x8*)(wt + (size_t)n * kC + k0 + kk);
        }
    };
    auto swr = [&](int d) {
        short* Ad = d ? As1 : As0;
        short* Bd = d ? Bs1 : Bs0;
        if (aAct) {
#pragma unroll
            for (int i = 0; i < 4; ++i)
                *(short4*)&Ad[arow * 36 + acol + 4 * i] = cvt4(la[i]);
        }
        {
            int n = tid >> 2, kk = (tid & 3) * 8;
            *(bf16x8*)&Bd[n * 36 + kk] = lb0;
        }
        if (tid < 256) {
            int c = tid + 512;
            int n = c >> 2, kk = (c & 3) * 8;
            *(bf16x8*)&Bd[n * 36 + kk] = lb1;
        }
    };

    f32x4 acc[8][3];
#pragma unroll
    for (int mt = 0; mt < 8; ++mt)
#pragma unroll
        for (int j = 0; j < 3; ++j) acc[mt][j] = f32x4{0.f, 0.f, 0.f, 0.f};

    auto mstep = [&](int d) {
        if (!mfmaAct) return;
        const short* Ad = d ? As1 : As0;
        const short* Bd = d ? Bs1 : Bs0;
        bf16x8 af[8];
#pragma unroll
        for (int mt = 0; mt < 8; ++mt)
            af[mt] = *(const bf16x8*)&Ad[(wm * 128 + mt * 16 + m16) * 36 + quad * 8];
#pragma unroll
        for (int j = 0; j < 3; ++j) {
            if (!kskip[j]) {
                const bf16x8 bfr =
                    *(const bf16x8*)&Bd[((wn * 3 + j) * 16 + m16) * 36 + quad * 8];
#pragma unroll
                for (int mt = 0; mt < 8; ++mt)
                    acc[mt][j] = __builtin_amdgcn_mfma_f32_16x16x32_bf16(
                        af[mt], bfr, acc[mt][j], 0, 0, 0);
            }
        }
    };

    glod(0);
    swr(0);
    __syncthreads();

    for (int s = 0; s < 12; ++s) {
        const int d = s & 1;
        if (s < 11) glod((s + 1) * 32);            // next tile in flight
        mstep(d);
        if (s < 11) swr(d ^ 1);
        __syncthreads();                            // last one also fences
    }                                               // staging-read vs home-write

    // epilogue: C-layout (col = m16 in-tile, rows = quad*4+r) -> swizzled homes
    if (mfmaAct) {
#pragma unroll
        for (int mt = 0; mt < 8; ++mt) {
            const int mbase = wm * 128 + mt * 16 + quad * 4;
#pragma unroll
            for (int j = 0; j < 3; ++j) {
                const int nt = wn * 3 + j;             // n-tile 0..11
                const int w  = nt >> 2;                // 0=q, 1=k, 2=v
                const int h  = (nt & 3) * 16 + m16;
                if (w == 2) {
                    float4 f = make_float4(acc[mt][j][0], acc[mt][j][1],
                                           acc[mt][j][2], acc[mt][j][3]);
                    *(short4*)&VTs[VI(h, mbase)] = cvt4(f);   // s = mbase..+3
                } else if (w == 1) {
                    if ((mbase >> 7) == half) {        // rows [t0, t0+128)
#pragma unroll
                        for (int r = 0; r < 4; ++r)
                            Ks[QI(mbase + r - t0, h)] = bf1(acc[mt][j][r]);
                    }
                } else {
#pragma unroll
                    for (int r = 0; r < 4; ++r)
                        Qs[QI(mbase + r, h)] = bf1(acc[mt][j][r]);
                }
            }
        }
    }
    __syncthreads();   // phase boundary: Qs/Ks/VTs all visible

    // -------- Phase 2: batch softmax + shfl-P (barrier-free) ----------
    const int wband = t0 + wave * 16;              // this wave's t-band
    const int ilast = wband >> 6;                  // wave-uniform
    const int jmaxd = wave & 3;                    // diag-tile jmax

    const bf16x8 ka0 = *(const bf16x8*)&Ks[QI(wave * 16 + m16, quad * 8)];
    const bf16x8 ka1 = *(const bf16x8*)&Ks[QI(wave * 16 + m16, quad * 8 + 32)];

    // all S' tiles in registers: S[i][j][r], s = i*64+j*16+quad*4+r, t = m16
    f32x4 S[4][4];
    const f32x4 Z = f32x4{0.f, 0.f, 0.f, 0.f};
#pragma unroll
    for (int i = 0; i < 4; ++i)
#pragma unroll
        for (int j = 0; j < 4; ++j) S[i][j] = Z;

    __builtin_amdgcn_s_setprio(1);
#pragma unroll
    for (int i = 0; i < 4; ++i) {
        if (i <= ilast) {
#pragma unroll
            for (int j = 0; j < 4; ++j) {
                if (i < ilast || j <= jmaxd) {
                    const int s = i * 64 + j * 16 + m16;
                    bf16x8 qb0 = *(const bf16x8*)&Qs[QI(s, quad * 8)];
                    bf16x8 qb1 = *(const bf16x8*)&Qs[QI(s, quad * 8 + 32)];
                    S[i][j] = __builtin_amdgcn_mfma_f32_16x16x32_bf16(qb0, ka0, S[i][j], 0, 0, 0);
                    S[i][j] = __builtin_amdgcn_mfma_f32_16x16x32_bf16(qb1, ka1, S[i][j], 0, 0, 0);
                }
            }
        }
    }
    __builtin_amdgcn_s_setprio(0);

    // diagonal mask on tile (ilast, jmaxd): s > t -> -inf   (static indices)
#pragma unroll
    for (int i = 0; i < 4; ++i)
#pragma unroll
        for (int j = 0; j < 4; ++j)
            if (i == ilast && j == jmaxd) {
#pragma unroll
                for (int r = 0; r < 4; ++r)
                    if (quad * 4 + r > m16) S[i][j][r] = -INFINITY;
            }

    // ONE global max over the whole row (t = wband + m16)
    float rm = -INFINITY;
#pragma unroll
    for (int i = 0; i < 4; ++i)
#pragma unroll
        for (int j = 0; j < 4; ++j)
            if (i <= ilast && (i < ilast || j <= jmaxd))
#pragma unroll
                for (int r = 0; r < 4; ++r) rm = fmaxf(rm, S[i][j][r]);
    rm = fmaxf(rm, __shfl_xor(rm, 16, 64));
    rm = fmaxf(rm, __shfl_xor(rm, 32, 64));

    // ONE exp pass in place + row sum (invalid tiles stay 0, masked -> exp=0)
    float l_ = 0.f;
#pragma unroll
    for (int i = 0; i < 4; ++i)
#pragma unroll
        for (int j = 0; j < 4; ++j)
            if (i <= ilast && (i < ilast || j <= jmaxd))
#pragma unroll
                for (int r = 0; r < 4; ++r) {
                    const float e = __expf(S[i][j][r] - rm);
                    S[i][j][r] = e;
                    l_ += e;
                }
    l_ += __shfl_xor(l_, 16, 64);
    l_ += __shfl_xor(l_, 32, 64);

    // PV: per i-tile, redistribute P via shfl (same-m16 cross-quad exchange).
    // Source lane (m16, qs) holds P[t=m16][sw=j*16+qs*4+r] in S[i][j][r].
    // Target A-frag word w of pf0: sw = quad*8+2w -> j=quad>>1,
    // qs=(quad&1)*2+(w>>1), pair r=2(w&1); pf1 same with j+2.
    f32x4 O[4];
#pragma unroll
    for (int i = 0; i < 4; ++i) O[i] = f32x4{0.f, 0.f, 0.f, 0.f};

    const int l0 = (quad & 1) * 32 + m16;          // shfl src: qs base lane
#pragma unroll
    for (int i = 0; i < 4; ++i) {
        if (i <= ilast) {
            unsigned Wp[4][2];
#pragma unroll
            for (int j = 0; j < 4; ++j)
#pragma unroll
                for (int u = 0; u < 2; ++u) {
                    __hip_bfloat162 t2 = __float22bfloat162_rn(
                        float2{S[i][j][2 * u], S[i][j][2 * u + 1]});
                    Wp[j][u] = *(unsigned*)&t2;
                }
            unsigned pw0[4], pw1[4];
#pragma unroll
            for (int j = 0; j < 4; ++j)
#pragma unroll
                for (int u = 0; u < 2; ++u) {
                    unsigned v0 = (unsigned)__shfl((int)Wp[j][u], l0, 64);
                    unsigned v1 = (unsigned)__shfl((int)Wp[j][u], l0 + 16, 64);
                    if ((quad >> 1) == j)     { pw0[u] = v0; pw0[2 + u] = v1; }
                    if ((quad >> 1) == j - 2) { pw1[u] = v0; pw1[2 + u] = v1; }
                }
            union { unsigned u[4]; bf16x8 v; } Pf0, Pf1;
#pragma unroll
            for (int w = 0; w < 4; ++w) { Pf0.u[w] = pw0[w]; Pf1.u[w] = pw1[w]; }

            __builtin_amdgcn_s_setprio(1);
#pragma unroll
            for (int ht = 0; ht < 4; ++ht) {
                bf16x8 vb0 = *(const bf16x8*)&VTs[VI(ht * 16 + m16, i * 64 + quad * 8)];
                bf16x8 vb1 = *(const bf16x8*)&VTs[VI(ht * 16 + m16, i * 64 + quad * 8 + 32)];
                O[ht] = __builtin_amdgcn_mfma_f32_16x16x32_bf16(Pf0.v, vb0, O[ht], 0, 0, 0);
                O[ht] = __builtin_amdgcn_mfma_f32_16x16x32_bf16(Pf1.v, vb1, O[ht], 0, 0, 0);
            }
            __builtin_amdgcn_s_setprio(0);
        }
    }

    // epilogue: 1/l broadcast from t=m16 holders, scale, store
    float lbc[4];
#pragma unroll
    for (int r = 0; r < 4; ++r)
        lbc[r] = __shfl(l_, (quad << 4) | (quad * 4 + r), 64);
#pragma unroll
    for (int r = 0; r < 4; ++r) {
        const float inv = 1.f / lbc[r];
        const size_t row = (size_t)(b * kT + wband + quad * 4 + r);
#pragma unroll
        for (int ht = 0; ht < 4; ++ht)
            out[row * kH + ht * 16 + m16] = O[ht][r] * inv;
    }
}

// ---------------------------------------------------------------------------
extern "C" void kernel_launch(void* const* d_in, const int* in_sizes, int n_in,
                              void* d_out, int out_size, void* d_ws, size_t ws_size,
                              hipStream_t stream) {
    const float* x  = (const float*)d_in[0];
    const float* Wq = (const float*)d_in[1];
    const float* Wk = (const float*)d_in[2];
    const float* Wv = (const float*)d_in[3];
    float* out = (float*)d_out;

    __hip_bfloat16* Wt = (__hip_bfloat16*)d_ws;    // 147 KB [n][k]

    prep_kernel<<<(192 * kC) / 256, 256, 0, stream>>>(Wq, Wk, Wv, Wt);
    fused_kernel<<<dim3(256), 512, 0, stream>>>(x, Wt, out);
}

// Round 8
// 133.842 us; speedup vs baseline: 1.6718x; 1.6718x over previous
//
#include <hip/hip_runtime.h>
#include <hip/hip_bf16.h>
#include <math.h>

constexpr int kB = 128;
constexpr int kT = 256;
constexpr int kC = 384;
constexpr int kH = 64;

using bf16x8 = __attribute__((ext_vector_type(8))) short;  // 8 bf16 = 4 VGPRs
using f32x4  = __attribute__((ext_vector_type(4))) float;

union BF8 { bf16x8 v; __hip_bfloat162 h[4]; };
union BF4 { short4 s; __hip_bfloat162 h[2]; };

__device__ inline bf16x8 cvt8(float4 a, float4 b) {
    BF8 u;
    u.h[0] = __float22bfloat162_rn(float2{a.x, a.y});
    u.h[1] = __float22bfloat162_rn(float2{a.z, a.w});
    u.h[2] = __float22bfloat162_rn(float2{b.x, b.y});
    u.h[3] = __float22bfloat162_rn(float2{b.z, b.w});
    return u.v;
}
__device__ inline short4 cvt4(float4 a) {
    BF4 u;
    u.h[0] = __float22bfloat162_rn(float2{a.x, a.y});
    u.h[1] = __float22bfloat162_rn(float2{a.z, a.w});
    return u.s;
}
__device__ inline short bf1(float f) {
    __hip_bfloat16 h = __float2bfloat16(f);
    return *(short*)&h;
}

// ---------------------------------------------------------------------------
// Kernel 0: Wt[n][k] bf16, n in [0,192) = (w*64+h), k in [0,384).
// Wk rows pre-scaled by 384^-0.5 (k only feeds scores).
// ---------------------------------------------------------------------------
__global__ void prep_kernel(const float* __restrict__ Wq,
                            const float* __restrict__ Wk,
                            const float* __restrict__ Wv,
                            __hip_bfloat16* __restrict__ Wt) {
    int idx = blockIdx.x * 256 + threadIdx.x;     // [0, 192*384)
    int n = idx / kC, c = idx % kC;
    int w = n >> 6, h = n & 63;
    const float* W = (w == 0) ? Wq : (w == 1) ? Wk : Wv;
    float val = W[c * kH + h];
    if (w == 1) val *= 0.051031036307982884f;     // 384^-0.5
    Wt[idx] = __float2bfloat16(val);
}

// ---------------------------------------------------------------------------
// Fused kernel — DE-STAGED phase 1: the 12-barrier LDS-staged projection is
// replaced by a barrier-free register GEMM. Each wave owns M/8 rows x ALL 12
// n-tiles (acc[2][12], accumulators in AGPRs exactly like R1's acc[8][3]):
//  - A-fragments: 8 floats straight from x (row touched ONCE per block,
//    no cross-wave redundancy) -> cvt8 -> MFMA A operand.
//  - B-fragments: 16 B rows of the 147 KB Wt, L2-hot across all 256 blocks.
// Phase 1 thus has ZERO barriers and ZERO LDS: 8 independent wave-streams
// per CU, 16 independent loads + 24 MFMA per K-step, latency hidden by
// in-wave ILP instead of the block-wide vmcnt(0)+barrier drains that R1-R6
// counters showed as the bottleneck (all pipes <12% busy). R7's lesson
// applied: (512,2) = 256 unified regs, NO tighter cap (R7's (512,4)=64 cap
// caused 286 MB of spill traffic; VGPR_Count 64 was the tell).
// The kernel has exactly ONE __syncthreads (phase boundary).
// Phase 2: R6 batch softmax + R7 shfl-P (both harness-verified), padded
// homes Qs/Ks/VTs = 89 KB LDS, 1 block/CU.
// Dead-K skip: heavy waves 0-3 skip K n-tiles j=4..7 (the epilogue's
// (mbase>>7)==half filter already excludes exactly those tiles).
// ---------------------------------------------------------------------------
__global__ __launch_bounds__(512, 2) void fused_kernel(
    const float* __restrict__ x, const __hip_bfloat16* __restrict__ Wt,
    float* __restrict__ out)
{
    __shared__ short Qs[256 * 72];      // [s][h]
    __shared__ short Ks[128 * 72];      // [t-t0][h]
    __shared__ short VTs[64 * 264];     // [h][s]

    const int bid  = blockIdx.x;
    const int b    = ((bid >> 4) << 3) | (bid & 7);   // batch
    const int half = ((bid >> 3) & 1) ^ 1;            // heavy (1) first
    const int t0   = half * 128;

    const int tid  = threadIdx.x;
    const int wave = tid >> 6, lane = tid & 63;
    const int m16  = lane & 15, quad = lane >> 4;
    const short* wt = (const short*)Wt;
    const float* xb = x + (size_t)b * kT * kC;

    // ---------------- Phase 1: de-staged projection (no barriers) ----------
    // wave owns rows [wbase, wbase + 16*nmt); heavy: 32 rows, light: 16.
    const int wbase = half ? wave * 32 : wave * 16;
    const float* xr0 = xb + (size_t)(wbase + m16) * kC;
    const float* xr1 = xb + (size_t)(wbase + 16 + m16) * kC;

    f32x4 acc[2][12];
#pragma unroll
    for (int mt = 0; mt < 2; ++mt)
#pragma unroll
        for (int j = 0; j < 12; ++j) acc[mt][j] = f32x4{0.f, 0.f, 0.f, 0.f};

    for (int ks = 0; ks < 12; ++ks) {
        const int k0 = ks * 32 + quad * 8;

        bf16x8 af0, af1;
        {
            float4 a = *(const float4*)(xr0 + k0);
            float4 c = *(const float4*)(xr0 + k0 + 4);
            af0 = cvt8(a, c);
        }
        if (half) {
            float4 a = *(const float4*)(xr1 + k0);
            float4 c = *(const float4*)(xr1 + k0 + 4);
            af1 = cvt8(a, c);
        }

#pragma unroll
        for (int j = 0; j < 12; ++j) {
            // dead-K skip: heavy waves 0-3's K projection (rows < 128) is
            // discarded by the epilogue filter -> skip load + MFMA.
            const bool skip = half && (wave < 4) && (j >= 4) && (j < 8);
            if (!skip) {
                const bf16x8 bfr =
                    *(const bf16x8*)(wt + (size_t)(j * 16 + m16) * kC + k0);
                acc[0][j] = __builtin_amdgcn_mfma_f32_16x16x32_bf16(
                    af0, bfr, acc[0][j], 0, 0, 0);
                if (half)
                    acc[1][j] = __builtin_amdgcn_mfma_f32_16x16x32_bf16(
                        af1, bfr, acc[1][j], 0, 0, 0);
            }
        }
    }

    // epilogue: C-layout (n-col = m16, m-rows = quad*4+r) -> padded LDS homes
#pragma unroll
    for (int mt = 0; mt < 2; ++mt) {
        if (mt == 0 || half) {
            const int mbase = wbase + mt * 16 + quad * 4;
#pragma unroll
            for (int j = 0; j < 12; ++j) {
                const int w = j >> 2;                  // 0=q, 1=k, 2=v
                const int h = (j & 3) * 16 + m16;
                if (w == 2) {
                    float4 f = make_float4(acc[mt][j][0], acc[mt][j][1],
                                           acc[mt][j][2], acc[mt][j][3]);
                    *(short4*)&VTs[h * 264 + mbase] = cvt4(f);   // s = mbase..+3
                } else if (w == 1) {
                    if ((mbase >> 7) == half) {        // rows [t0, t0+128)
#pragma unroll
                        for (int r = 0; r < 4; ++r)
                            Ks[(mbase + r - t0) * 72 + h] = bf1(acc[mt][j][r]);
                    }
                } else {
#pragma unroll
                    for (int r = 0; r < 4; ++r)
                        Qs[(mbase + r) * 72 + h] = bf1(acc[mt][j][r]);
                }
            }
        }
    }
    __syncthreads();   // THE phase boundary: Qs/Ks/VTs all visible

    // -------- Phase 2: batch softmax + shfl-P (barrier-free, R6/R7) --------
    const int wband = t0 + wave * 16;              // this wave's t-band
    const int ilast = wband >> 6;                  // wave-uniform
    const int jmaxd = wave & 3;                    // diag-tile jmax

    const bf16x8 ka0 = *(const bf16x8*)&Ks[(wave * 16 + m16) * 72 + quad * 8];
    const bf16x8 ka1 = *(const bf16x8*)&Ks[(wave * 16 + m16) * 72 + quad * 8 + 32];

    // all S' tiles in registers: S[i][j][r], s = i*64+j*16+quad*4+r, t = m16
    f32x4 S[4][4];
    const f32x4 Z = f32x4{0.f, 0.f, 0.f, 0.f};
#pragma unroll
    for (int i = 0; i < 4; ++i)
#pragma unroll
        for (int j = 0; j < 4; ++j) S[i][j] = Z;

    __builtin_amdgcn_s_setprio(1);
#pragma unroll
    for (int i = 0; i < 4; ++i) {
        if (i <= ilast) {
#pragma unroll
            for (int j = 0; j < 4; ++j) {
                if (i < ilast || j <= jmaxd) {
                    const int s = i * 64 + j * 16 + m16;
                    bf16x8 qb0 = *(const bf16x8*)&Qs[s * 72 + quad * 8];
                    bf16x8 qb1 = *(const bf16x8*)&Qs[s * 72 + quad * 8 + 32];
                    S[i][j] = __builtin_amdgcn_mfma_f32_16x16x32_bf16(qb0, ka0, S[i][j], 0, 0, 0);
                    S[i][j] = __builtin_amdgcn_mfma_f32_16x16x32_bf16(qb1, ka1, S[i][j], 0, 0, 0);
                }
            }
        }
    }
    __builtin_amdgcn_s_setprio(0);

    // diagonal mask on tile (ilast, jmaxd): s > t -> -inf   (static indices)
#pragma unroll
    for (int i = 0; i < 4; ++i)
#pragma unroll
        for (int j = 0; j < 4; ++j)
            if (i == ilast && j == jmaxd) {
#pragma unroll
                for (int r = 0; r < 4; ++r)
                    if (quad * 4 + r > m16) S[i][j][r] = -INFINITY;
            }

    // ONE global max over the whole row (t = wband + m16)
    float rm = -INFINITY;
#pragma unroll
    for (int i = 0; i < 4; ++i)
#pragma unroll
        for (int j = 0; j < 4; ++j)
            if (i <= ilast && (i < ilast || j <= jmaxd))
#pragma unroll
                for (int r = 0; r < 4; ++r) rm = fmaxf(rm, S[i][j][r]);
    rm = fmaxf(rm, __shfl_xor(rm, 16, 64));
    rm = fmaxf(rm, __shfl_xor(rm, 32, 64));

    // ONE exp pass in place + row sum (invalid tiles stay 0, masked -> exp=0)
    float l_ = 0.f;
#pragma unroll
    for (int i = 0; i < 4; ++i)
#pragma unroll
        for (int j = 0; j < 4; ++j)
            if (i <= ilast && (i < ilast || j <= jmaxd))
#pragma unroll
                for (int r = 0; r < 4; ++r) {
                    const float e = __expf(S[i][j][r] - rm);
                    S[i][j][r] = e;
                    l_ += e;
                }
    l_ += __shfl_xor(l_, 16, 64);
    l_ += __shfl_xor(l_, 32, 64);

    // PV: per i-tile, redistribute P via shfl (same-m16 cross-quad exchange).
    // Source lane (m16, qs) holds P[t=m16][sw=j*16+qs*4+r] in S[i][j][r].
    // Target A-frag word w of pf0: sw = quad*8+2w -> j=quad>>1,
    // qs=(quad&1)*2+(w>>1), pair r=2(w&1); pf1 same with j+2.
    f32x4 O[4];
#pragma unroll
    for (int i = 0; i < 4; ++i) O[i] = f32x4{0.f, 0.f, 0.f, 0.f};

    const int l0 = (quad & 1) * 32 + m16;          // shfl src: qs base lane
#pragma unroll
    for (int i = 0; i < 4; ++i) {
        if (i <= ilast) {
            unsigned Wp[4][2];
#pragma unroll
            for (int j = 0; j < 4; ++j)
#pragma unroll
                for (int u = 0; u < 2; ++u) {
                    __hip_bfloat162 t2 = __float22bfloat162_rn(
                        float2{S[i][j][2 * u], S[i][j][2 * u + 1]});
                    Wp[j][u] = *(unsigned*)&t2;
                }
            unsigned pw0[4], pw1[4];
#pragma unroll
            for (int j = 0; j < 4; ++j)
#pragma unroll
                for (int u = 0; u < 2; ++u) {
                    unsigned v0 = (unsigned)__shfl((int)Wp[j][u], l0, 64);
                    unsigned v1 = (unsigned)__shfl((int)Wp[j][u], l0 + 16, 64);
                    if ((quad >> 1) == j)     { pw0[u] = v0; pw0[2 + u] = v1; }
                    if ((quad >> 1) == j - 2) { pw1[u] = v0; pw1[2 + u] = v1; }
                }
            union { unsigned u[4]; bf16x8 v; } Pf0, Pf1;
#pragma unroll
            for (int w = 0; w < 4; ++w) { Pf0.u[w] = pw0[w]; Pf1.u[w] = pw1[w]; }

            __builtin_amdgcn_s_setprio(1);
#pragma unroll
            for (int ht = 0; ht < 4; ++ht) {
                bf16x8 vb0 = *(const bf16x8*)&VTs[(ht * 16 + m16) * 264 + i * 64 + quad * 8];
                bf16x8 vb1 = *(const bf16x8*)&VTs[(ht * 16 + m16) * 264 + i * 64 + quad * 8 + 32];
                O[ht] = __builtin_amdgcn_mfma_f32_16x16x32_bf16(Pf0.v, vb0, O[ht], 0, 0, 0);
                O[ht] = __builtin_amdgcn_mfma_f32_16x16x32_bf16(Pf1.v, vb1, O[ht], 0, 0, 0);
            }
            __builtin_amdgcn_s_setprio(0);
        }
    }

    // epilogue: 1/l broadcast from t=m16 holders, scale, store
    float lbc[4];
#pragma unroll
    for (int r = 0; r < 4; ++r)
        lbc[r] = __shfl(l_, (quad << 4) | (quad * 4 + r), 64);
#pragma unroll
    for (int r = 0; r < 4; ++r) {
        const float inv = 1.f / lbc[r];
        const size_t row = (size_t)(b * kT + wband + quad * 4 + r);
#pragma unroll
        for (int ht = 0; ht < 4; ++ht)
            out[row * kH + ht * 16 + m16] = O[ht][r] * inv;
    }
}

// ---------------------------------------------------------------------------
extern "C" void kernel_launch(void* const* d_in, const int* in_sizes, int n_in,
                              void* d_out, int out_size, void* d_ws, size_t ws_size,
                              hipStream_t stream) {
    const float* x  = (const float*)d_in[0];
    const float* Wq = (const float*)d_in[1];
    const float* Wk = (const float*)d_in[2];
    const float* Wv = (const float*)d_in[3];
    float* out = (float*)d_out;

    __hip_bfloat16* Wt = (__hip_bfloat16*)d_ws;    // 147 KB [n][k]

    prep_kernel<<<(192 * kC) / 256, 256, 0, stream>>>(Wq, Wk, Wv, Wt);
    fused_kernel<<<dim3(256), 512, 0, stream>>>(x, Wt, out);
}

// Round 10
// 109.940 us; speedup vs baseline: 2.0353x; 1.2174x over previous
//
#include <hip/hip_runtime.h>
#include <hip/hip_bf16.h>
#include <math.h>

constexpr int kB = 128;
constexpr int kT = 256;
constexpr int kC = 384;
constexpr int kH = 64;

using bf16x8 = __attribute__((ext_vector_type(8))) short;  // 8 bf16 = 4 VGPRs
using f32x4  = __attribute__((ext_vector_type(4))) float;

union BF4 { short4 s; __hip_bfloat162 h[2]; };

__device__ inline short4 cvt4(float4 a) {
    BF4 u;
    u.h[0] = __float22bfloat162_rn(float2{a.x, a.y});
    u.h[1] = __float22bfloat162_rn(float2{a.z, a.w});
    return u.s;
}
__device__ inline short bf1(float f) {
    __hip_bfloat16 h = __float2bfloat16(f);
    return *(short*)&h;
}

// ---------------------------------------------------------------------------
// Kernel 0: Wt[n][k] bf16, n in [0,192) = (w*64+h), k in [0,384).
// Wk rows pre-scaled by 384^-0.5 * log2(e): scores come out of QK^T already
// in log2 domain, so softmax uses raw v_exp_f32 (exp2) with no per-element
// multiply. exp2(S~ - m~) == exp(S - m) exactly (positive scale preserves
// the max and the ratio), so softmax semantics are bit-equivalent.
// ---------------------------------------------------------------------------
__global__ void prep_kernel(const float* __restrict__ Wq,
                            const float* __restrict__ Wk,
                            const float* __restrict__ Wv,
                            __hip_bfloat16* __restrict__ Wt) {
    int idx = blockIdx.x * 256 + threadIdx.x;     // [0, 192*384)
    int n = idx / kC, c = idx % kC;
    int w = n >> 6, h = n & 63;
    const float* W = (w == 0) ? Wq : (w == 1) ? Wk : Wv;
    float val = W[c * kH + h];
    if (w == 1) val *= 0.07362222374744683f;      // 384^-0.5 * log2(e)
    Wt[idx] = __float2bfloat16(val);
}

// ---------------------------------------------------------------------------
// Fused kernel — R6 structure (best measured: dur 110.7) with the exp2 fold.
// Phase 1: M x 192 GEMM (M = 256 heavy / 128 light), BK=32, 12 LDS
// double-buffered K-steps, XCD pair swizzle, dead-K skip.
// Phase 2: BATCH softmax — all S-tiles in registers (S[4][4] f32x4, static
// indices, wave-uniform guards), ONE max reduce (2 shfl_xor), ONE exp2 pass
// (plain exp2f -> single v_exp_f32; NOTE: __exp2f does not exist in HIP,
// R9 compile error), ONE sum (2 shfl_xor), then PV via the dead-As P buffer.
// Session ledger: more waves (R2) x, split kernels (R3/4) x, destaged
// phase 1 (R8) x, 2-deep pipeline (R5) 0, reg caps <256 (R7) fatal-spill.
// ---------------------------------------------------------------------------
__global__ __launch_bounds__(512, 2) void fused_kernel(
    const float* __restrict__ x, const __hip_bfloat16* __restrict__ Wt,
    float* __restrict__ out)
{
    __shared__ short Qs[256 * 72];      // [s][h]
    __shared__ short Ks[128 * 72];      // [t-t0][h]
    __shared__ short VTs[64 * 264];     // [h][s]
    __shared__ short As[2][256 * 36];   // x tile bf16 [m][kk], stride 36
    __shared__ short Bs[2][192 * 36];   // Wt tile    [n][kk], stride 36

    const int bid  = blockIdx.x;
    const int b    = ((bid >> 4) << 3) | (bid & 7);   // batch
    const int half = ((bid >> 3) & 1) ^ 1;            // heavy (1) first
    const int t0   = half * 128;

    const int tid  = threadIdx.x;
    const int wave = tid >> 6, lane = tid & 63;
    const int m16  = lane & 15, quad = lane >> 4;
    const int wm = wave & 1, wn = wave >> 1;       // m-half, 3-n-tile slice
    const short* wt = (const short*)Wt;
    const float* xb = x + (size_t)b * kT * kC;

    // wave-uniform activity masks for the light half (M = 128)
    const bool mfmaAct = (half == 1) || (wm == 0);

    // dead-K: heavy half's rows 0-127 K-projection is discarded -> skip
    bool kskip[3];
#pragma unroll
    for (int j = 0; j < 3; ++j) {
        const int nt = wn * 3 + j;
        kskip[j] = (half == 1) && (wm == 0) && (nt >= 4) && (nt < 8);
    }

    // ---------------- Phase 1: projection ----------------
    const int arow = tid >> 1, acol = (tid & 1) * 16;
    const bool aAct = (half == 1) || (arow < 128);

    float4 la[4]; bf16x8 lb0, lb1;
    auto glod = [&](int k0) {
        if (aAct) {
#pragma unroll
            for (int i = 0; i < 4; ++i)
                la[i] = *(const float4*)(xb + (size_t)arow * kC + k0 + acol + 4 * i);
        }
        {
            int n = tid >> 2, kk = (tid & 3) * 8;
            lb0 = *(const bf16x8*)(wt + (size_t)n * kC + k0 + kk);
        }
        if (tid < 256) {
            int c = tid + 512;
            int n = c >> 2, kk = (c & 3) * 8;
            lb1 = *(const bf16x8*)(wt + (size_t)n * kC + k0 + kk);
        }
    };
    auto swr = [&](int d) {
        if (aAct) {
#pragma unroll
            for (int i = 0; i < 4; ++i)
                *(short4*)&As[d][arow * 36 + acol + 4 * i] = cvt4(la[i]);
        }
        {
            int n = tid >> 2, kk = (tid & 3) * 8;
            *(bf16x8*)&Bs[d][n * 36 + kk] = lb0;
        }
        if (tid < 256) {
            int c = tid + 512;
            int n = c >> 2, kk = (c & 3) * 8;
            *(bf16x8*)&Bs[d][n * 36 + kk] = lb1;
        }
    };

    f32x4 acc[8][3];
#pragma unroll
    for (int mt = 0; mt < 8; ++mt)
#pragma unroll
        for (int j = 0; j < 3; ++j) acc[mt][j] = f32x4{0.f, 0.f, 0.f, 0.f};

    glod(0);
    swr(0);
    __syncthreads();

    for (int s = 0; s < 12; ++s) {
        const int d = s & 1;
        if (s < 11) glod((s + 1) * 32);            // next tile in flight

        if (mfmaAct) {
            bf16x8 af[8];
#pragma unroll
            for (int mt = 0; mt < 8; ++mt)
                af[mt] = *(const bf16x8*)&As[d][(wm * 128 + mt * 16 + m16) * 36 + quad * 8];
#pragma unroll
            for (int j = 0; j < 3; ++j) {
                if (!kskip[j]) {
                    const bf16x8 bfr =
                        *(const bf16x8*)&Bs[d][((wn * 3 + j) * 16 + m16) * 36 + quad * 8];
#pragma unroll
                    for (int mt = 0; mt < 8; ++mt)
                        acc[mt][j] = __builtin_amdgcn_mfma_f32_16x16x32_bf16(
                            af[mt], bfr, acc[mt][j], 0, 0, 0);
                }
            }
        }

        if (s < 11) swr(d ^ 1);
        __syncthreads();
    }

    // epilogue: C-layout (col = m16 in-tile, rows = quad*4+r) -> LDS homes
    if (mfmaAct) {
#pragma unroll
        for (int mt = 0; mt < 8; ++mt) {
            const int mbase = wm * 128 + mt * 16 + quad * 4;
#pragma unroll
            for (int j = 0; j < 3; ++j) {
                const int nt = wn * 3 + j;             // n-tile 0..11
                const int w  = nt >> 2;                // 0=q, 1=k, 2=v
                const int h  = (nt & 3) * 16 + m16;
                if (w == 2) {
                    float4 f = make_float4(acc[mt][j][0], acc[mt][j][1],
                                           acc[mt][j][2], acc[mt][j][3]);
                    *(short4*)&VTs[h * 264 + mbase] = cvt4(f);   // s = mbase..+3
                } else if (w == 1) {
                    if ((mbase >> 7) == half) {        // rows [t0, t0+128)
#pragma unroll
                        for (int r = 0; r < 4; ++r)
                            Ks[(mbase + r - t0) * 72 + h] = bf1(acc[mt][j][r]);
                    }
                } else {
#pragma unroll
                    for (int r = 0; r < 4; ++r)
                        Qs[(mbase + r) * 72 + h] = bf1(acc[mt][j][r]);
                }
            }
        }
    }
    __syncthreads();   // phase boundary: Qs/Ks/VTs all visible

    // -------- Phase 2: attention, BATCH softmax (barrier-free) ----------
    const int wband = t0 + wave * 16;              // this wave's t-band
    short* Pb = &As[0][0] + wave * 1152;           // dead As: 16x72 bf16/wave

    const bf16x8 ka0 = *(const bf16x8*)&Ks[(wave * 16 + m16) * 72 + quad * 8];
    const bf16x8 ka1 = *(const bf16x8*)&Ks[(wave * 16 + m16) * 72 + quad * 8 + 32];

    const int ilast = wband >> 6;                  // wave-uniform
    const int jmaxd = wave & 3;                    // diag-tile jmax

    // all S' tiles in registers: S[i][j][r], s = i*64+j*16+quad*4+r, t = m16
    f32x4 S[4][4];
    const f32x4 Z = f32x4{0.f, 0.f, 0.f, 0.f};
#pragma unroll
    for (int i = 0; i < 4; ++i)
#pragma unroll
        for (int j = 0; j < 4; ++j) S[i][j] = Z;

    __builtin_amdgcn_s_setprio(1);
#pragma unroll
    for (int i = 0; i < 4; ++i) {
        if (i <= ilast) {
#pragma unroll
            for (int j = 0; j < 4; ++j) {
                if (i < ilast || j <= jmaxd) {
                    const int s = i * 64 + j * 16 + m16;
                    bf16x8 qb0 = *(const bf16x8*)&Qs[s * 72 + quad * 8];
                    bf16x8 qb1 = *(const bf16x8*)&Qs[s * 72 + quad * 8 + 32];
                    S[i][j] = __builtin_amdgcn_mfma_f32_16x16x32_bf16(qb0, ka0, S[i][j], 0, 0, 0);
                    S[i][j] = __builtin_amdgcn_mfma_f32_16x16x32_bf16(qb1, ka1, S[i][j], 0, 0, 0);
                }
            }
        }
    }
    __builtin_amdgcn_s_setprio(0);

    // diagonal mask on tile (ilast, jmaxd): s > t -> -inf   (static indices)
#pragma unroll
    for (int i = 0; i < 4; ++i)
#pragma unroll
        for (int j = 0; j < 4; ++j)
            if (i == ilast && j == jmaxd) {
#pragma unroll
                for (int r = 0; r < 4; ++r)
                    if (quad * 4 + r > m16) S[i][j][r] = -INFINITY;
            }

    // ONE global max over the whole row (t = wband + m16); scores are in
    // log2 domain (Wk prescale), max is order-preserved
    float rm = -INFINITY;
#pragma unroll
    for (int i = 0; i < 4; ++i)
#pragma unroll
        for (int j = 0; j < 4; ++j)
            if (i <= ilast && (i < ilast || j <= jmaxd))
#pragma unroll
                for (int r = 0; r < 4; ++r) rm = fmaxf(rm, S[i][j][r]);
    rm = fmaxf(rm, __shfl_xor(rm, 16, 64));
    rm = fmaxf(rm, __shfl_xor(rm, 32, 64));

    // ONE exp2 pass in place + row sum (exp2(S~-m~) == exp(S-m) exactly;
    // exp2f lowers to a single v_exp_f32, no per-element multiply)
    float l_ = 0.f;
#pragma unroll
    for (int i = 0; i < 4; ++i)
#pragma unroll
        for (int j = 0; j < 4; ++j)
            if (i <= ilast && (i < ilast || j <= jmaxd))
#pragma unroll
                for (int r = 0; r < 4; ++r) {
                    const float e = exp2f(S[i][j][r] - rm);
                    S[i][j][r] = e;
                    l_ += e;
                }
    l_ += __shfl_xor(l_, 16, 64);
    l_ += __shfl_xor(l_, 32, 64);

    // PV: per i-tile, pack P -> Pb, read back as A-fragment, 8 MFMAs
    f32x4 O[4];
#pragma unroll
    for (int i = 0; i < 4; ++i) O[i] = f32x4{0.f, 0.f, 0.f, 0.f};

#pragma unroll
    for (int i = 0; i < 4; ++i) {
        if (i <= ilast) {
#pragma unroll
            for (int j = 0; j < 4; ++j)
#pragma unroll
                for (int p = 0; p < 2; ++p) {
                    __hip_bfloat162 w = __float22bfloat162_rn(
                        float2{S[i][j][2 * p], S[i][j][2 * p + 1]});
                    *(__hip_bfloat162*)&Pb[m16 * 72 + j * 16 + quad * 4 + 2 * p] = w;
                }
            bf16x8 pf0 = *(const bf16x8*)&Pb[m16 * 72 + quad * 8];
            bf16x8 pf1 = *(const bf16x8*)&Pb[m16 * 72 + quad * 8 + 32];

            __builtin_amdgcn_s_setprio(1);
#pragma unroll
            for (int ht = 0; ht < 4; ++ht) {
                bf16x8 vb0 = *(const bf16x8*)&VTs[(ht * 16 + m16) * 264 + i * 64 + quad * 8];
                bf16x8 vb1 = *(const bf16x8*)&VTs[(ht * 16 + m16) * 264 + i * 64 + quad * 8 + 32];
                O[ht] = __builtin_amdgcn_mfma_f32_16x16x32_bf16(pf0, vb0, O[ht], 0, 0, 0);
                O[ht] = __builtin_amdgcn_mfma_f32_16x16x32_bf16(pf1, vb1, O[ht], 0, 0, 0);
            }
            __builtin_amdgcn_s_setprio(0);
        }
    }

    // epilogue: 1/l broadcast from t=m16 holders, scale, store
    float lbc[4];
#pragma unroll
    for (int r = 0; r < 4; ++r)
        lbc[r] = __shfl(l_, (quad << 4) | (quad * 4 + r), 64);
#pragma unroll
    for (int r = 0; r < 4; ++r) {
        const float inv = 1.f / lbc[r];
        const size_t row = (size_t)(b * kT + wband + quad * 4 + r);
#pragma unroll
        for (int ht = 0; ht < 4; ++ht)
            out[row * kH + ht * 16 + m16] = O[ht][r] * inv;
    }
}

// ---------------------------------------------------------------------------
extern "C" void kernel_launch(void* const* d_in, const int* in_sizes, int n_in,
                              void* d_out, int out_size, void* d_ws, size_t ws_size,
                              hipStream_t stream) {
    const float* x  = (const float*)d_in[0];
    const float* Wq = (const float*)d_in[1];
    const float* Wk = (const float*)d_in[2];
    const float* Wv = (const float*)d_in[3];
    float* out = (float*)d_out;

    __hip_bfloat16* Wt = (__hip_bfloat16*)d_ws;    // 147 KB [n][k]

    prep_kernel<<<(192 * kC) / 256, 256, 0, stream>>>(Wq, Wk, Wv, Wt);
    fused_kernel<<<dim3(256), 512, 0, stream>>>(x, Wt, out);
}